// Round 1
// baseline (366.988 us; speedup 1.0000x reference)
//
#include <hip/hip_runtime.h>
#include <hip/hip_bf16.h>
#include <stdint.h>

// GNN 2-layer: out = relu(h@Ws1^T + A@(h@Wn1^T)), h = relu(x@Ws0^T + (A@x)@Wn0^T)
// A = [8192][8192] int32 {0,1}. HBM-bound on reading A twice (512 MB -> ~81us floor).

typedef __attribute__((ext_vector_type(8))) short bf16x8;   // 8 bf16 in 4 VGPRs
typedef __attribute__((ext_vector_type(4))) float f32x4;

union U4 { uint4 u; int4 i; bf16x8 b; };

__device__ inline f32x4 mfma16(bf16x8 a, bf16x8 b, f32x4 c) {
    return __builtin_amdgcn_mfma_f32_16x16x32_bf16(a, b, c, 0, 0, 0);
}

__device__ inline unsigned short f2bf(float f) {
    union { float f; unsigned int u; } v; v.f = f;
    unsigned int u = v.u;
    return (unsigned short)((u + 0x7FFFu + ((u >> 16) & 1u)) >> 16);  // RNE
}

// ---------------------------------------------------------------------------
// Kernel 0: convert x -> x_bf16 [8192][128] and xT_bf16 [128][8192];
//           convert 4 weight matrices -> wcat bf16 (ws0|wn0|ws1|wn1).
// ---------------------------------------------------------------------------
__global__ __launch_bounds__(256) void convert_kernel(
    const float* __restrict__ x,
    const float* __restrict__ w0, const float* __restrict__ w1,
    const float* __restrict__ w2, const float* __restrict__ w3,
    unsigned short* __restrict__ xb, unsigned short* __restrict__ xT,
    unsigned short* __restrict__ wcat)
{
    const int bid = blockIdx.x, t = threadIdx.x;
    if (bid < 128) {
        // 64 rows of x per block: write x_bf16 linear + xT via LDS transpose
        __shared__ unsigned short XT[128][72];   // padded rows (144B, 16B-aligned)
        const int base = bid * 8192;             // 64 rows * 128 cols
        #pragma unroll
        for (int i = 0; i < 32; ++i) {
            int off = i * 256 + t;
            unsigned short b = f2bf(x[base + off]);
            xb[base + off] = b;
            XT[off & 127][off >> 7] = b;         // [col][local row]
        }
        __syncthreads();
        const int c = t >> 1, half = t & 1;      // c: 0..127, half selects 32 shorts
        const uint4* src = (const uint4*)&XT[c][half * 32];
        uint4* dst = (uint4*)(xT + c * 8192 + bid * 64 + half * 32);
        dst[0] = src[0]; dst[1] = src[1]; dst[2] = src[2]; dst[3] = src[3];
    } else {
        // weights: 131072 elements over 8 blocks
        int w = (bid - 128) * 16384 + t;
        #pragma unroll
        for (int i = 0; i < 64; ++i, w += 256) {
            float v;
            if      (w < 32768)  v = w0[w];
            else if (w < 65536)  v = w1[w - 32768];
            else if (w < 98304)  v = w2[w - 65536];
            else                 v = w3[w - 98304];
            wcat[w] = f2bf(v);
        }
    }
}

// ---------------------------------------------------------------------------
// Kernel 1 (used twice): C[8192][128] += A_chunk @ B, B given transposed as
// BT [128][8192] bf16. Split-K = 8, BM = 64, grid = 128*8 = 1024 blocks.
// Each wave owns 16 rows; stages its OWN rows into private LDS region ->
// no __syncthreads anywhere. A int32 -> bf16 via (a0|a1<<16)*0x3F80.
// B-fragments streamed from L2 straight to registers (BT is 2MB, L2/L3-hot).
// ---------------------------------------------------------------------------
__global__ __launch_bounds__(256) void neigh_gemm(
    const int* __restrict__ A, const __hip_bfloat16* __restrict__ BT,
    float* __restrict__ C)
{
    __shared__ unsigned short At[2][64 * 32];    // bf16 tile, 4KB per buffer
    const int t    = threadIdx.x;
    const int lane = t & 63;
    const int wave = t >> 6;
    const int bid  = blockIdx.x;
    const int mbase = (bid >> 3) << 6;           // 0..8128 step 64
    const int kbase = (bid & 7) << 10;           // k-chunk of 1024

    // --- staging map: thread -> (row = t>>2, logical 16B slot = t&3) ---
    const int srow  = t >> 2;                    // 0..63 (wave w covers its own rows)
    const int sslot = t & 3;                     // 8 ints each
    const int sswz  = (srow >> 1) & 3;           // XOR swizzle for bank spread
    const int* gA = A + (mbase + srow) * 8192 + kbase + sslot * 8;
    unsigned short* lw = &At[0][srow * 32 + ((sslot ^ sswz) << 3)];

    // --- fragment read map: lane -> row = wave*16+(lane&15), k-slot = lane>>4 ---
    const int frow  = (wave << 4) + (lane & 15);
    const int fslot = (lane >> 4) ^ ((frow >> 1) & 3);
    const unsigned short* lr = &At[0][frow * 32 + (fslot << 3)];

    // --- B fragment base: col = lane&15 (within 16-tile), k = (lane>>4)*8 ---
    const __hip_bfloat16* gB = BT + (lane & 15) * 8192 + kbase + ((lane >> 4) << 3);

    f32x4 acc[8];
    #pragma unroll
    for (int n = 0; n < 8; ++n) acc[n] = (f32x4){0.f, 0.f, 0.f, 0.f};

    // prologue: stage k-tile 0 into buf 0
    {
        int4 p0 = *(const int4*)(gA);
        int4 p1 = *(const int4*)(gA + 4);
        gA += 32;
        U4 w;
        w.u.x = (unsigned)(p0.x | (p0.y << 16)) * 0x3F80u;
        w.u.y = (unsigned)(p0.z | (p0.w << 16)) * 0x3F80u;
        w.u.z = (unsigned)(p1.x | (p1.y << 16)) * 0x3F80u;
        w.u.w = (unsigned)(p1.z | (p1.w << 16)) * 0x3F80u;
        *(uint4*)lw = w.u;
    }

    const int NIT = 32;                          // 1024 / BK(32)
    for (int it = 0; it < NIT; ++it) {
        const int cur = it & 1;
        // prefetch next A tile (global -> regs, latency hidden under MFMA)
        int4 n0, n1;
        if (it + 1 < NIT) {
            n0 = *(const int4*)(gA);
            n1 = *(const int4*)(gA + 4);
            gA += 32;
        }
        // B fragments for this k-step (8 n-tiles)
        U4 bf[8];
        const __hip_bfloat16* gBk = gB + it * 32;
        #pragma unroll
        for (int n = 0; n < 8; ++n)
            bf[n].u = *(const uint4*)(gBk + n * (16 * 8192));
        // A fragment from LDS (swizzled ds_read_b128)
        U4 af;
        af.u = *(const uint4*)(lr + cur * (64 * 32));
        #pragma unroll
        for (int n = 0; n < 8; ++n)
            acc[n] = mfma16(af.b, bf[n].b, acc[n]);
        // convert + stage next tile into other buffer
        if (it + 1 < NIT) {
            U4 w;
            w.u.x = (unsigned)(n0.x | (n0.y << 16)) * 0x3F80u;
            w.u.y = (unsigned)(n0.z | (n0.w << 16)) * 0x3F80u;
            w.u.z = (unsigned)(n1.x | (n1.y << 16)) * 0x3F80u;
            w.u.w = (unsigned)(n1.z | (n1.w << 16)) * 0x3F80u;
            *(uint4*)(lw + (cur ^ 1) * (64 * 32)) = w.u;
        }
    }

    // epilogue: fp32 atomic accumulate (split-K)
    const int col = lane & 15;
    const int r0  = mbase + (wave << 4) + ((lane >> 4) << 2);
    #pragma unroll
    for (int n = 0; n < 8; ++n)
        #pragma unroll
        for (int r = 0; r < 4; ++r)
            atomicAdd(&C[(r0 + r) * 128 + (n << 4) + col], acc[n][r]);
}

// ---------------------------------------------------------------------------
// Kernel 2: h = relu(x@Ws0^T + neigh1@Wn0^T) -> bf16 [8192][256]
// Block tile 32m x 256n, 4 waves (2m x 2n). K = 128 + 128. No LDS.
// ---------------------------------------------------------------------------
__global__ __launch_bounds__(256) void h_kernel(
    const unsigned short* __restrict__ xb, const float* __restrict__ ng,
    const unsigned short* __restrict__ wcat, unsigned short* __restrict__ h)
{
    const int t = threadIdx.x, lane = t & 63, wave = t >> 6;
    const int wm = wave & 1, wn = wave >> 1;
    const int mbase = blockIdx.x * 32 + wm * 16;
    const int nbase = wn * 128;
    const int row = mbase + (lane & 15);
    const int ko  = (lane >> 4) << 3;

    f32x4 acc[8];
    #pragma unroll
    for (int n = 0; n < 8; ++n) acc[n] = (f32x4){0.f, 0.f, 0.f, 0.f};

    // self part: x (bf16) @ Ws0^T
    const unsigned short* xl = xb + row * 128 + ko;
    const unsigned short* w0 = wcat + (nbase + (lane & 15)) * 128 + ko;
    #pragma unroll
    for (int ks = 0; ks < 4; ++ks) {
        U4 a; a.u = *(const uint4*)(xl + ks * 32);
        #pragma unroll
        for (int n = 0; n < 8; ++n) {
            U4 b; b.u = *(const uint4*)(w0 + n * (16 * 128) + ks * 32);
            acc[n] = mfma16(a.b, b.b, acc[n]);
        }
    }
    // neighbor part: neigh1 (fp32 -> bf16) @ Wn0^T
    const float* nl = ng + row * 128 + ko;
    const unsigned short* w1 = wcat + 32768 + (nbase + (lane & 15)) * 128 + ko;
    #pragma unroll
    for (int ks = 0; ks < 4; ++ks) {
        float4 f0 = *(const float4*)(nl + ks * 32);
        float4 f1 = *(const float4*)(nl + ks * 32 + 4);
        U4 a;
        a.u.x = (unsigned)f2bf(f0.x) | ((unsigned)f2bf(f0.y) << 16);
        a.u.y = (unsigned)f2bf(f0.z) | ((unsigned)f2bf(f0.w) << 16);
        a.u.z = (unsigned)f2bf(f1.x) | ((unsigned)f2bf(f1.y) << 16);
        a.u.w = (unsigned)f2bf(f1.z) | ((unsigned)f2bf(f1.w) << 16);
        #pragma unroll
        for (int n = 0; n < 8; ++n) {
            U4 b; b.u = *(const uint4*)(w1 + n * (16 * 128) + ks * 32);
            acc[n] = mfma16(a.b, b.b, acc[n]);
        }
    }
    // relu + store bf16
    #pragma unroll
    for (int n = 0; n < 8; ++n)
        #pragma unroll
        for (int r = 0; r < 4; ++r) {
            int m = mbase + ((lane >> 4) << 2) + r;
            int c = nbase + (n << 4) + (lane & 15);
            float v = acc[n][r];
            h[m * 256 + c] = f2bf(v > 0.f ? v : 0.f);
        }
}

// ---------------------------------------------------------------------------
// Kernel 3: pT = (h @ Wn1^T)^T -> bf16 [128][8192]  (transposed for neigh_gemm)
// Block tile 32m x 128n, 4 waves (2m x 2n). K = 256.
// ---------------------------------------------------------------------------
__global__ __launch_bounds__(256) void p_kernel(
    const unsigned short* __restrict__ h, const unsigned short* __restrict__ wn1,
    unsigned short* __restrict__ pT)
{
    __shared__ unsigned short PT[128][40];       // [n][m] padded
    const int t = threadIdx.x, lane = t & 63, wave = t >> 6;
    const int wm = wave & 1, wn = wave >> 1;
    const int mbase = blockIdx.x * 32 + wm * 16;
    const int nbase = wn * 64;
    const int ko = (lane >> 4) << 3;

    f32x4 acc[4];
    #pragma unroll
    for (int n = 0; n < 4; ++n) acc[n] = (f32x4){0.f, 0.f, 0.f, 0.f};

    const unsigned short* hl = h + (mbase + (lane & 15)) * 256 + ko;
    const unsigned short* wl = wn1 + (nbase + (lane & 15)) * 256 + ko;
    #pragma unroll
    for (int ks = 0; ks < 8; ++ks) {
        U4 a; a.u = *(const uint4*)(hl + ks * 32);
        #pragma unroll
        for (int n = 0; n < 4; ++n) {
            U4 b; b.u = *(const uint4*)(wl + n * (16 * 256) + ks * 32);
            acc[n] = mfma16(a.b, b.b, acc[n]);
        }
    }
    // transpose through LDS: lane holds 4 consecutive m at fixed n
    const int m0 = wm * 16 + ((lane >> 4) << 2);
    #pragma unroll
    for (int n = 0; n < 4; ++n) {
        int c = nbase + (n << 4) + (lane & 15);
        unsigned int u0 = (unsigned)f2bf(acc[n][0]) | ((unsigned)f2bf(acc[n][1]) << 16);
        unsigned int u1 = (unsigned)f2bf(acc[n][2]) | ((unsigned)f2bf(acc[n][3]) << 16);
        *(uint2*)&PT[c][m0] = make_uint2(u0, u1);
    }
    __syncthreads();
    const int c = t >> 1, half = t & 1;
    const uint4* src = (const uint4*)&PT[c][half * 16];
    uint4* dst = (uint4*)(pT + c * 8192 + blockIdx.x * 32 + half * 16);
    dst[0] = src[0]; dst[1] = src[1];
}

// ---------------------------------------------------------------------------
// Kernel 4: out = relu(h@Ws1^T + t) fp32 [8192][128]
// ---------------------------------------------------------------------------
__global__ __launch_bounds__(256) void out_kernel(
    const unsigned short* __restrict__ h, const unsigned short* __restrict__ ws1,
    const float* __restrict__ tacc, float* __restrict__ out)
{
    const int t = threadIdx.x, lane = t & 63, wave = t >> 6;
    const int wm = wave & 1, wn = wave >> 1;
    const int mbase = blockIdx.x * 32 + wm * 16;
    const int nbase = wn * 64;
    const int ko = (lane >> 4) << 3;

    f32x4 acc[4];
    #pragma unroll
    for (int n = 0; n < 4; ++n) acc[n] = (f32x4){0.f, 0.f, 0.f, 0.f};

    const unsigned short* hl = h + (mbase + (lane & 15)) * 256 + ko;
    const unsigned short* wl = ws1 + (nbase + (lane & 15)) * 256 + ko;
    #pragma unroll
    for (int ks = 0; ks < 8; ++ks) {
        U4 a; a.u = *(const uint4*)(hl + ks * 32);
        #pragma unroll
        for (int n = 0; n < 4; ++n) {
            U4 b; b.u = *(const uint4*)(wl + n * (16 * 256) + ks * 32);
            acc[n] = mfma16(a.b, b.b, acc[n]);
        }
    }
    #pragma unroll
    for (int n = 0; n < 4; ++n)
        #pragma unroll
        for (int r = 0; r < 4; ++r) {
            int m = mbase + ((lane >> 4) << 2) + r;
            int c = nbase + (n << 4) + (lane & 15);
            int idx = m * 128 + c;
            float v = acc[n][r] + tacc[idx];
            out[idx] = v > 0.f ? v : 0.f;
        }
}

// ---------------------------------------------------------------------------
extern "C" void kernel_launch(void* const* d_in, const int* in_sizes, int n_in,
                              void* d_out, int out_size, void* d_ws, size_t ws_size,
                              hipStream_t stream)
{
    const float* x   = (const float*)d_in[0];
    const int*   adj = (const int*)d_in[1];
    const float* ws0 = (const float*)d_in[2];
    const float* wn0 = (const float*)d_in[3];
    const float* ws1 = (const float*)d_in[4];
    const float* wn1 = (const float*)d_in[5];
    float* out = (float*)d_out;

    char* ws = (char*)d_ws;
    float*          neigh1 = (float*)(ws);                        // 4 MB
    float*          tacc   = (float*)(ws + (4 << 20));            // 4 MB
    unsigned short* xb     = (unsigned short*)(ws + (8 << 20));   // 2 MB
    unsigned short* xT     = (unsigned short*)(ws + (10 << 20));  // 2 MB
    unsigned short* h      = (unsigned short*)(ws + (12 << 20));  // 4 MB
    unsigned short* pT     = (unsigned short*)(ws + (16 << 20));  // 2 MB
    unsigned short* wcat   = (unsigned short*)(ws + (18 << 20));  // 256 KB

    // zero the split-K accumulators
    hipMemsetAsync(ws, 0, 8 << 20, stream);

    convert_kernel<<<136, 256, 0, stream>>>(x, ws0, wn0, ws1, wn1, xb, xT, wcat);
    neigh_gemm<<<1024, 256, 0, stream>>>(adj, (const __hip_bfloat16*)xT, neigh1);
    h_kernel<<<256, 256, 0, stream>>>(xb, neigh1, wcat, h);
    p_kernel<<<256, 256, 0, stream>>>(h, wcat + 98304, pT);
    neigh_gemm<<<1024, 256, 0, stream>>>(adj, (const __hip_bfloat16*)pT, tacc);
    out_kernel<<<256, 256, 0, stream>>>(h, wcat + 65536, tacc, out);
}